// Round 18
// baseline (61.664 us; speedup 1.0000x reference)
//
#include <hip/hip_runtime.h>
#include <stdint.h>

#define O_DIM 512
#define D_DIM 128
#define LR 0.01f
// 1 / (2 * sigma^2), sigma = 256 -> 1/131072
#define INV2SIG2 7.62939453125e-6f

#define LDS_GRPS 18    // grps 0..17  (72 panel-rows) -> LDS (144 KB)
#define HOLD_GRPS 14   // grps 18..31 (56 panel-rows) -> registers (56 VGPR)
#define RR_GRPS 32     // grps 32..63 (128 panel-rows)-> L3 re-read in phase B

typedef float f32x4 __attribute__((ext_vector_type(4)));

// ---------------- fast path ----------------
// ws layout: [0, 1 MiB) : dist[512][512] float
//
// Panel-contiguous fused kernel (page-efficient), three-tier residency:
//   All column-owner variants (R10-R17) plateau at ~4.2 TB/s: they read W in
//   512B segments strided by 256KB (~25% DRAM page efficiency), while linear
//   kernels on this problem hit ~7 TB/s. This block owns a 4-col x 256-row
//   panel: thread t -> (rr = t>>7, jcl = (t>>5)&3, i32 = t&31); each
//   row-group access is 8KB CONTIGUOUS (4 rows x 2KB full DRAM pages), for
//   loads, stores, and the L3 re-read alike.
//   Residency per block (512KB panel): grps 0..17 LDS, 18..31 registers
//   (R15-proven 56-VGPR hold), 32..63 re-read via L3 in phase B.
//   grid 256 x 512thr; jp = bid>>1 (cols jp*4..+3), h = bid&1 (rows h*256..).
__global__ __launch_bounds__(512) void som_fused(
    const float* __restrict__ X,
    const float* __restrict__ W,
    float* __restrict__ dist,
    float* __restrict__ outW)
{
    const int jp  = blockIdx.x >> 1;      // 0..127 column panel
    const int h   = blockIdx.x & 1;       // row half
    const int jc0 = jp * 4;
    const int t   = threadIdx.x;
    const int wave = t >> 6;              // 0..7
    const int lane = t & 63;
    const int i32 = lane & 31;            // d-slice
    const int d0  = i32 * 4;
    const int jcl = (t >> 5) & 3;         // local column 0..3
    const int rr  = t >> 7;               // 0..3 row-in-group
    const int jg  = jc0 + jcl;            // global column
    const int b0  = h * 256;              // row base; b = b0 + grp*4 + rr

    __shared__ f32x4 ldsW4[LDS_GRPS * 4 * 128];  // 147456 B (panel-row*128 + jcl*32 + i32)
    __shared__ f32x4 sacc[8][64];                // 8192 B
    __shared__ f32x4 sS[128];                    // 2048 B (jcl*32 + i32)

    f32x4 acc = {0.f, 0.f, 0.f, 0.f};

    // ---------------- phase A part 1: grps 0..17 -> LDS (3 batches of 6) ----------------
    #pragma unroll
    for (int bt = 0; bt < 3; ++bt) {
        f32x4 wv[6], xv[6];
        #pragma unroll
        for (int u = 0; u < 6; ++u) {
            const int b = b0 + (bt * 6 + u) * 4 + rr;
            wv[u] = *(const f32x4*)(W + ((size_t)b * O_DIM + jg) * D_DIM + d0);
            xv[u] = *(const f32x4*)(X + (size_t)b * D_DIM + d0);
        }
        #pragma unroll
        for (int u = 0; u < 6; ++u) {
            const int grp = bt * 6 + u;
            const int b = b0 + grp * 4 + rr;
            const f32x4 dx = wv[u] - xv[u];
            float sum = dx.x * dx.x;
            sum = fmaf(dx.y, dx.y, sum);
            sum = fmaf(dx.z, dx.z, sum);
            sum = fmaf(dx.w, dx.w, sum);
            sum += __shfl_xor(sum, 1, 64);
            sum += __shfl_xor(sum, 2, 64);
            sum += __shfl_xor(sum, 4, 64);
            sum += __shfl_xor(sum, 8, 64);
            sum += __shfl_xor(sum, 16, 64);
            if (i32 == 0) dist[(size_t)b * O_DIM + jg] = sum;
            const float c = LR * __expf(-sum * INV2SIG2);
            acc -= c * dx;
            ldsW4[(grp * 4 + rr) * 128 + jcl * 32 + i32] = wv[u];
        }
    }

    // ---------------- phase A part 2: grps 18..31 -> registers (4,4,4,2) ----------------
    f32x4 whold[HOLD_GRPS];
    #pragma unroll
    for (int bt = 0; bt < 4; ++bt) {
        const int n = (bt < 3) ? 4 : 2;
        f32x4 xv[4];
        #pragma unroll
        for (int u = 0; u < 4; ++u) {
            if (u < n) {
                const int idx = bt * 4 + u;
                const int b = b0 + (LDS_GRPS + idx) * 4 + rr;
                whold[idx] = *(const f32x4*)(W + ((size_t)b * O_DIM + jg) * D_DIM + d0);
                xv[u] = *(const f32x4*)(X + (size_t)b * D_DIM + d0);
            }
        }
        #pragma unroll
        for (int u = 0; u < 4; ++u) {
            if (u < n) {
                const int idx = bt * 4 + u;
                const int b = b0 + (LDS_GRPS + idx) * 4 + rr;
                const f32x4 dx = whold[idx] - xv[u];
                float sum = dx.x * dx.x;
                sum = fmaf(dx.y, dx.y, sum);
                sum = fmaf(dx.z, dx.z, sum);
                sum = fmaf(dx.w, dx.w, sum);
                sum += __shfl_xor(sum, 1, 64);
                sum += __shfl_xor(sum, 2, 64);
                sum += __shfl_xor(sum, 4, 64);
                sum += __shfl_xor(sum, 8, 64);
                sum += __shfl_xor(sum, 16, 64);
                if (i32 == 0) dist[(size_t)b * O_DIM + jg] = sum;
                const float c = LR * __expf(-sum * INV2SIG2);
                acc -= c * dx;
            }
        }
    }

    // ---------------- phase A part 3: grps 32..63 transient (8 batches of 4) ----------------
    for (int bt = 0; bt < 8; ++bt) {
        f32x4 wv[4], xv[4];
        #pragma unroll
        for (int u = 0; u < 4; ++u) {
            const int b = b0 + (32 + bt * 4 + u) * 4 + rr;
            wv[u] = *(const f32x4*)(W + ((size_t)b * O_DIM + jg) * D_DIM + d0);
            xv[u] = *(const f32x4*)(X + (size_t)b * D_DIM + d0);
        }
        #pragma unroll
        for (int u = 0; u < 4; ++u) {
            const int b = b0 + (32 + bt * 4 + u) * 4 + rr;
            const f32x4 dx = wv[u] - xv[u];
            float sum = dx.x * dx.x;
            sum = fmaf(dx.y, dx.y, sum);
            sum = fmaf(dx.z, dx.z, sum);
            sum = fmaf(dx.w, dx.w, sum);
            sum += __shfl_xor(sum, 1, 64);
            sum += __shfl_xor(sum, 2, 64);
            sum += __shfl_xor(sum, 4, 64);
            sum += __shfl_xor(sum, 8, 64);
            sum += __shfl_xor(sum, 16, 64);
            if (i32 == 0) dist[(size_t)b * O_DIM + jg] = sum;
            const float c = LR * __expf(-sum * INV2SIG2);
            acc -= c * dx;
        }
    }

    // ---- S reduce: sum the 4 rr-subgroups (waves w, w+2, w+4, w+6) ----
    sacc[wave][lane] = acc;
    __syncthreads();
    if (t < 128) {
        const int qj = t >> 5;            // col 0..3
        const int qi = t & 31;
        const int l  = (qj & 1) * 32 + qi;
        const int w0 = qj >> 1;
        sS[t] = sacc[w0][l] + sacc[w0 + 2][l] + sacc[w0 + 4][l] + sacc[w0 + 6][l];
    }
    __syncthreads();
    const f32x4 s4 = sS[jcl * 32 + i32];

    // ---------------- phase B: grps 18..31 from registers ----------------
    #pragma unroll
    for (int idx = 0; idx < HOLD_GRPS; ++idx) {
        const int b = b0 + (LDS_GRPS + idx) * 4 + rr;
        __builtin_nontemporal_store(
            whold[idx] + s4, (f32x4*)(outW + ((size_t)b * O_DIM + jg) * D_DIM + d0));
    }
    // ---------------- phase B: grps 0..17 from LDS ----------------
    #pragma unroll 6
    for (int grp = 0; grp < LDS_GRPS; ++grp) {
        const int b = b0 + grp * 4 + rr;
        const f32x4 wv = ldsW4[(grp * 4 + rr) * 128 + jcl * 32 + i32];
        __builtin_nontemporal_store(
            wv + s4, (f32x4*)(outW + ((size_t)b * O_DIM + jg) * D_DIM + d0));
    }
    // ---------------- phase B: grps 32..63 via L3 (4 batches of 8) ----------------
    for (int bt = 0; bt < 4; ++bt) {
        f32x4 wx[8];
        #pragma unroll
        for (int u = 0; u < 8; ++u) {
            const int b = b0 + (32 + bt * 8 + u) * 4 + rr;
            wx[u] = *(const f32x4*)(W + ((size_t)b * O_DIM + jg) * D_DIM + d0);
        }
        #pragma unroll
        for (int u = 0; u < 8; ++u) {
            const int b = b0 + (32 + bt * 8 + u) * 4 + rr;
            __builtin_nontemporal_store(
                wx[u] + s4, (f32x4*)(outW + ((size_t)b * O_DIM + jg) * D_DIM + d0));
        }
    }
}

// row-wise argmin over j for each b
__global__ __launch_bounds__(64) void som_argmin(
    const float* __restrict__ dist,
    float* __restrict__ out)
{
    const int b = blockIdx.x;
    const int lane = threadIdx.x;
    unsigned long long best = ~0ull;
    #pragma unroll
    for (int k = 0; k < 8; ++k) {
        const int jj = k * 64 + lane;
        const float s = dist[(size_t)b * O_DIM + jj];
        const unsigned long long key =
            ((unsigned long long)__float_as_uint(s) << 32) | (unsigned int)jj;
        best = key < best ? key : best;
    }
    #pragma unroll
    for (int m = 32; m >= 1; m >>= 1) {
        const unsigned long long o = __shfl_xor(best, m, 64);
        best = o < best ? o : best;
    }
    if (lane == 0) out[b] = (float)(unsigned int)(best & 0xFFFFFFFFull);
}

// ---------------- fallback path (atomics, small ws) ----------------

__global__ __launch_bounds__(256) void som_pass1_atomic(
    const float* __restrict__ X, const float* __restrict__ W,
    float* __restrict__ S, unsigned long long* __restrict__ wkey)
{
    const int j = blockIdx.x >> 2, chunk = blockIdx.x & 3;
    const int wave = threadIdx.x >> 6, lane = threadIdx.x & 63;
    const int d0 = lane * 2;
    float accx = 0.f, accy = 0.f;
    const int b_end = chunk * 128 + 128;
    for (int b = chunk * 128 + wave; b < b_end; b += 4) {
        const float2 w2 = *(const float2*)(W + ((size_t)b * O_DIM + j) * D_DIM + d0);
        const float2 x2 = *(const float2*)(X + (size_t)b * D_DIM + d0);
        const float dx = w2.x - x2.x, dy = w2.y - x2.y;
        float s = dx * dx + dy * dy;
        #pragma unroll
        for (int m = 32; m >= 1; m >>= 1) s += __shfl_xor(s, m, 64);
        if (lane == 0)
            atomicMin(&wkey[b], ((unsigned long long)__float_as_uint(s) << 32) | (unsigned)j);
        const float c = LR * __expf(-s * INV2SIG2);
        accx -= c * dx; accy -= c * dy;
    }
    __shared__ float sacc[D_DIM];
    if (threadIdx.x < D_DIM) sacc[threadIdx.x] = 0.f;
    __syncthreads();
    atomicAdd(&sacc[d0], accx); atomicAdd(&sacc[d0 + 1], accy);
    __syncthreads();
    if (threadIdx.x < D_DIM) atomicAdd(&S[(size_t)j * D_DIM + threadIdx.x], sacc[threadIdx.x]);
}

__global__ __launch_bounds__(256) void som_pass2_atomic(
    const float* __restrict__ W, const float* __restrict__ S,
    const unsigned long long* __restrict__ wkey, float* __restrict__ out)
{
    const size_t tid = (size_t)blockIdx.x * blockDim.x + threadIdx.x;
    if (tid < O_DIM) out[tid] = (float)(unsigned int)(wkey[tid] & 0xFFFFFFFFull);
    float* __restrict__ outW = out + O_DIM;
    const size_t total4 = (size_t)O_DIM * O_DIM * D_DIM / 4;
    const size_t stride = (size_t)gridDim.x * blockDim.x;
    for (size_t i = tid; i < total4; i += stride) {
        const size_t e = i * 4;
        const float4 w4 = *(const float4*)(W + e);
        const float4 s4 = *(const float4*)(S + (e & (size_t)(O_DIM * D_DIM - 1)));
        float4 o4 = {w4.x + s4.x, w4.y + s4.y, w4.z + s4.z, w4.w + s4.w};
        *(float4*)(outW + e) = o4;
    }
}

extern "C" void kernel_launch(void* const* d_in, const int* in_sizes, int n_in,
                              void* d_out, int out_size, void* d_ws, size_t ws_size,
                              hipStream_t stream)
{
    const float* X = (const float*)d_in[0];   // (512, 128)
    const float* W = (const float*)d_in[1];   // (512, 512, 128)
    float* out = (float*)d_out;               // 512 winners + 512*512*128 weights

    const size_t DIST_BYTES = (size_t)O_DIM * O_DIM * sizeof(float);   // 1 MiB

    if (ws_size >= DIST_BYTES) {
        float* dist = (float*)d_ws;
        som_fused <<<dim3(256), dim3(512), 0, stream>>>(X, W, dist, out + O_DIM);
        som_argmin<<<dim3(512), dim3(64),  0, stream>>>(dist, out);
    } else {
        float* S = (float*)d_ws;
        unsigned long long* wkey =
            (unsigned long long*)((char*)d_ws + (size_t)O_DIM * D_DIM * sizeof(float));
        hipMemsetAsync(S, 0, (size_t)O_DIM * D_DIM * sizeof(float), stream);
        hipMemsetAsync(wkey, 0xFF, (size_t)O_DIM * sizeof(unsigned long long), stream);
        som_pass1_atomic<<<dim3(2048), dim3(256), 0, stream>>>(X, W, S, wkey);
        som_pass2_atomic<<<dim3(2048), dim3(256), 0, stream>>>(W, S, wkey, out);
    }
}

// Round 19
// 54.411 us; speedup vs baseline: 1.1333x; 1.1333x over previous
//
#include <hip/hip_runtime.h>
#include <stdint.h>

#define O_DIM 512
#define D_DIM 128
#define LR 0.01f
// 1 / (2 * sigma^2), sigma = 256 -> 1/131072
#define INV2SIG2 7.62939453125e-6f

#define LDS_GRPS 18    // grps 0..17  (rows 0..287)  -> LDS (144 KB)
#define HOLD_GRPS 14   // grps 18..31 (rows 288..511)-> registers (56 VGPR)

typedef float f32x4 __attribute__((ext_vector_type(4)));

// ---------------- fast path ----------------
// ws layout: [0, 1 MiB) : dist[512][512] float
//
// Fused column-owner kernel (R15 structure: hybrid LDS + register residency,
// zero W re-read, 54.75 us) + XCD-aware column swizzle:
//   Column accesses are 512B segments at 256KB stride. With the default
//   bid%8 -> XCD round-robin, ADJACENT columns land on DIFFERENT XCDs/L2s,
//   so the four 512B segments of each 2KB DRAM page are issued by different
//   L2s -> fragmented HBM request stream -> rate pinned at ~4.2 TB/s while
//   traffic counters look clean (R11-R16: occupancy/MLP levers all null).
//   Swizzle j = (bid&7)*64 + (bid>>3): XCD x owns contiguous columns
//   [64x, 64x+64); its ~32 co-resident blocks access 32 adjacent 512B
//   segments per row = whole 2KB pages per channel, reads and writes alike.
//   Bijective for 512 = 8*64.
__global__ __launch_bounds__(512) void som_fused(
    const float* __restrict__ X,
    const float* __restrict__ W,
    float* __restrict__ dist,
    float* __restrict__ outW)
{
    const int j    = ((blockIdx.x & 7) << 6) | (blockIdx.x >> 3);  // XCD swizzle
    const int t    = threadIdx.x;
    const int wave = t >> 6;              // 0..7
    const int lane = t & 63;
    const int g    = lane >> 5;           // row-subgroup 0..1
    const int i32  = lane & 31;           // d-slice index
    const int d0   = i32 * 4;             // floats [d0, d0+4)
    const int rb   = wave * 2 + g;        // row-in-group 0..15; b = grp*16 + rb

    __shared__ float ldsW[LDS_GRPS * 16 * D_DIM];  // 147456 B
    __shared__ float sacc[8][D_DIM];               // 4096 B
    __shared__ float sS[D_DIM];                    // 512 B

    f32x4 acc = {0.f, 0.f, 0.f, 0.f};

    // ---------------- phase A part 1: grps 0..17 -> LDS (3 batches of 6) ----------------
    #pragma unroll
    for (int bt = 0; bt < 3; ++bt) {
        f32x4 wv[6], xv[6];
        #pragma unroll
        for (int u = 0; u < 6; ++u) {
            const int b = (bt * 6 + u) * 16 + rb;
            wv[u] = *(const f32x4*)(W + ((size_t)b * O_DIM + j) * D_DIM + d0);
            xv[u] = *(const f32x4*)(X + (size_t)b * D_DIM + d0);
        }
        #pragma unroll
        for (int u = 0; u < 6; ++u) {
            const int b = (bt * 6 + u) * 16 + rb;
            const f32x4 dx = wv[u] - xv[u];
            float sum = dx.x * dx.x;
            sum = fmaf(dx.y, dx.y, sum);
            sum = fmaf(dx.z, dx.z, sum);
            sum = fmaf(dx.w, dx.w, sum);
            sum += __shfl_xor(sum, 1, 64);
            sum += __shfl_xor(sum, 2, 64);
            sum += __shfl_xor(sum, 4, 64);
            sum += __shfl_xor(sum, 8, 64);
            sum += __shfl_xor(sum, 16, 64);

            if (i32 == 0) dist[(size_t)b * O_DIM + j] = sum;

            const float c = LR * __expf(-sum * INV2SIG2);
            acc -= c * dx;                    // += c * (x - w)

            *(f32x4*)(&ldsW[b * D_DIM + d0]) = wv[u];
        }
    }

    // ---------------- phase A part 2: grps 18..31 -> registers (4,4,4,2) ----------------
    f32x4 whold[HOLD_GRPS];
    #pragma unroll
    for (int bt = 0; bt < 4; ++bt) {
        const int n = (bt < 3) ? 4 : 2;
        f32x4 xv[4];
        #pragma unroll
        for (int u = 0; u < 4; ++u) {
            if (u < n) {
                const int idx = bt * 4 + u;
                const int b = (LDS_GRPS + idx) * 16 + rb;
                whold[idx] = *(const f32x4*)(W + ((size_t)b * O_DIM + j) * D_DIM + d0);
                xv[u] = *(const f32x4*)(X + (size_t)b * D_DIM + d0);
            }
        }
        #pragma unroll
        for (int u = 0; u < 4; ++u) {
            if (u < n) {
                const int idx = bt * 4 + u;
                const int b = (LDS_GRPS + idx) * 16 + rb;
                const f32x4 dx = whold[idx] - xv[u];
                float sum = dx.x * dx.x;
                sum = fmaf(dx.y, dx.y, sum);
                sum = fmaf(dx.z, dx.z, sum);
                sum = fmaf(dx.w, dx.w, sum);
                sum += __shfl_xor(sum, 1, 64);
                sum += __shfl_xor(sum, 2, 64);
                sum += __shfl_xor(sum, 4, 64);
                sum += __shfl_xor(sum, 8, 64);
                sum += __shfl_xor(sum, 16, 64);

                if (i32 == 0) dist[(size_t)b * O_DIM + j] = sum;

                const float c = LR * __expf(-sum * INV2SIG2);
                acc -= c * dx;                // += c * (x - w)
            }
        }
    }

    // ---- fold the two row-subgroups (lane ^ 32) ----
    acc.x += __shfl_xor(acc.x, 32, 64);
    acc.y += __shfl_xor(acc.y, 32, 64);
    acc.z += __shfl_xor(acc.z, 32, 64);
    acc.w += __shfl_xor(acc.w, 32, 64);

    if (lane < 32) *(f32x4*)(&sacc[wave][d0]) = acc;
    __syncthreads();
    if (t < D_DIM) {
        float v = sacc[0][t];
        #pragma unroll
        for (int w = 1; w < 8; ++w) v += sacc[w][t];
        sS[t] = v;
    }
    __syncthreads();
    const f32x4 s4 = *(const f32x4*)(sS + d0);

    // ---------------- phase B: rows 288..511 from registers first ----------------
    #pragma unroll
    for (int idx = 0; idx < HOLD_GRPS; ++idx) {
        const int b = (LDS_GRPS + idx) * 16 + rb;
        __builtin_nontemporal_store(
            whold[idx] + s4, (f32x4*)(outW + ((size_t)b * O_DIM + j) * D_DIM + d0));
    }
    // ---------------- phase B: rows 0..287 from LDS ----------------
    #pragma unroll 6
    for (int grp = 0; grp < LDS_GRPS; ++grp) {
        const int b = grp * 16 + rb;
        const f32x4 wv = *(const f32x4*)(&ldsW[b * D_DIM + d0]);
        __builtin_nontemporal_store(
            wv + s4, (f32x4*)(outW + ((size_t)b * O_DIM + j) * D_DIM + d0));
    }
}

// row-wise argmin over j for each b
__global__ __launch_bounds__(64) void som_argmin(
    const float* __restrict__ dist,
    float* __restrict__ out)
{
    const int b = blockIdx.x;
    const int lane = threadIdx.x;
    unsigned long long best = ~0ull;
    #pragma unroll
    for (int k = 0; k < 8; ++k) {
        const int jj = k * 64 + lane;
        const float s = dist[(size_t)b * O_DIM + jj];
        const unsigned long long key =
            ((unsigned long long)__float_as_uint(s) << 32) | (unsigned int)jj;
        best = key < best ? key : best;
    }
    #pragma unroll
    for (int m = 32; m >= 1; m >>= 1) {
        const unsigned long long o = __shfl_xor(best, m, 64);
        best = o < best ? o : best;
    }
    if (lane == 0) out[b] = (float)(unsigned int)(best & 0xFFFFFFFFull);
}

// ---------------- fallback path (atomics, small ws) ----------------

__global__ __launch_bounds__(256) void som_pass1_atomic(
    const float* __restrict__ X, const float* __restrict__ W,
    float* __restrict__ S, unsigned long long* __restrict__ wkey)
{
    const int j = blockIdx.x >> 2, chunk = blockIdx.x & 3;
    const int wave = threadIdx.x >> 6, lane = threadIdx.x & 63;
    const int d0 = lane * 2;
    float accx = 0.f, accy = 0.f;
    const int b_end = chunk * 128 + 128;
    for (int b = chunk * 128 + wave; b < b_end; b += 4) {
        const float2 w2 = *(const float2*)(W + ((size_t)b * O_DIM + j) * D_DIM + d0);
        const float2 x2 = *(const float2*)(X + (size_t)b * D_DIM + d0);
        const float dx = w2.x - x2.x, dy = w2.y - x2.y;
        float s = dx * dx + dy * dy;
        #pragma unroll
        for (int m = 32; m >= 1; m >>= 1) s += __shfl_xor(s, m, 64);
        if (lane == 0)
            atomicMin(&wkey[b], ((unsigned long long)__float_as_uint(s) << 32) | (unsigned)j);
        const float c = LR * __expf(-s * INV2SIG2);
        accx -= c * dx; accy -= c * dy;
    }
    __shared__ float sacc[D_DIM];
    if (threadIdx.x < D_DIM) sacc[threadIdx.x] = 0.f;
    __syncthreads();
    atomicAdd(&sacc[d0], accx); atomicAdd(&sacc[d0 + 1], accy);
    __syncthreads();
    if (threadIdx.x < D_DIM) atomicAdd(&S[(size_t)j * D_DIM + threadIdx.x], sacc[threadIdx.x]);
}

__global__ __launch_bounds__(256) void som_pass2_atomic(
    const float* __restrict__ W, const float* __restrict__ S,
    const unsigned long long* __restrict__ wkey, float* __restrict__ out)
{
    const size_t tid = (size_t)blockIdx.x * blockDim.x + threadIdx.x;
    if (tid < O_DIM) out[tid] = (float)(unsigned int)(wkey[tid] & 0xFFFFFFFFull);
    float* __restrict__ outW = out + O_DIM;
    const size_t total4 = (size_t)O_DIM * O_DIM * D_DIM / 4;
    const size_t stride = (size_t)gridDim.x * blockDim.x;
    for (size_t i = tid; i < total4; i += stride) {
        const size_t e = i * 4;
        const float4 w4 = *(const float4*)(W + e);
        const float4 s4 = *(const float4*)(S + (e & (size_t)(O_DIM * D_DIM - 1)));
        float4 o4 = {w4.x + s4.x, w4.y + s4.y, w4.z + s4.z, w4.w + s4.w};
        *(float4*)(outW + e) = o4;
    }
}

extern "C" void kernel_launch(void* const* d_in, const int* in_sizes, int n_in,
                              void* d_out, int out_size, void* d_ws, size_t ws_size,
                              hipStream_t stream)
{
    const float* X = (const float*)d_in[0];   // (512, 128)
    const float* W = (const float*)d_in[1];   // (512, 512, 128)
    float* out = (float*)d_out;               // 512 winners + 512*512*128 weights

    const size_t DIST_BYTES = (size_t)O_DIM * O_DIM * sizeof(float);   // 1 MiB

    if (ws_size >= DIST_BYTES) {
        float* dist = (float*)d_ws;
        som_fused <<<dim3(512), dim3(512), 0, stream>>>(X, W, dist, out + O_DIM);
        som_argmin<<<dim3(512), dim3(64),  0, stream>>>(dist, out);
    } else {
        float* S = (float*)d_ws;
        unsigned long long* wkey =
            (unsigned long long*)((char*)d_ws + (size_t)O_DIM * D_DIM * sizeof(float));
        hipMemsetAsync(S, 0, (size_t)O_DIM * D_DIM * sizeof(float), stream);
        hipMemsetAsync(wkey, 0xFF, (size_t)O_DIM * sizeof(unsigned long long), stream);
        som_pass1_atomic<<<dim3(2048), dim3(256), 0, stream>>>(X, W, S, wkey);
        som_pass2_atomic<<<dim3(2048), dim3(256), 0, stream>>>(W, S, wkey, out);
    }
}